// Round 8
// baseline (80350.128 us; speedup 1.0000x reference)
//
#include <hip/hip_runtime.h>
#include <cstdint>
#include <cstddef>

#define SEQ   2048
#define BATCH 64
#define HID   512

// ---------------------------------------------------------------------------
// proj GEMM: C[m][n] = sum_k A[m][k] * W[n][k] + bias[n]
// ---------------------------------------------------------------------------
__global__ __launch_bounds__(256)
void proj_gemm(const float* __restrict__ A, const float* __restrict__ W,
               const float* __restrict__ bias, float* __restrict__ C)
{
    __shared__ float As[16][132];
    __shared__ float Bs[16][132];
    const int t  = threadIdx.x;
    const int bm = blockIdx.x >> 2;
    const int bn = blockIdx.x & 3;
    const int m0 = bm * 128;
    const int n0 = bn * 128;
    const int tn = t & 15;
    const int tm = t >> 4;

    float acc[8][8];
#pragma unroll
    for (int i = 0; i < 8; ++i)
#pragma unroll
        for (int j = 0; j < 8; ++j) acc[i][j] = 0.f;

    const int lrow = t >> 2;
    const int lk4  = t & 3;

    for (int kk = 0; kk < 512; kk += 16) {
#pragma unroll
        for (int i = 0; i < 2; ++i) {
            const int row = lrow + i * 64;
            float4 va = *(const float4*)&A[(size_t)(m0 + row) * 512 + kk + lk4 * 4];
            As[lk4 * 4 + 0][row] = va.x;
            As[lk4 * 4 + 1][row] = va.y;
            As[lk4 * 4 + 2][row] = va.z;
            As[lk4 * 4 + 3][row] = va.w;
            float4 vb = *(const float4*)&W[(size_t)(n0 + row) * 512 + kk + lk4 * 4];
            Bs[lk4 * 4 + 0][row] = vb.x;
            Bs[lk4 * 4 + 1][row] = vb.y;
            Bs[lk4 * 4 + 2][row] = vb.z;
            Bs[lk4 * 4 + 3][row] = vb.w;
        }
        __syncthreads();
#pragma unroll
        for (int k = 0; k < 16; ++k) {
            float4 a0 = *(const float4*)&As[k][tm * 8];
            float4 a1 = *(const float4*)&As[k][tm * 8 + 4];
            float4 b0 = *(const float4*)&Bs[k][tn * 4];
            float4 b1 = *(const float4*)&Bs[k][64 + tn * 4];
            float ar[8] = {a0.x, a0.y, a0.z, a0.w, a1.x, a1.y, a1.z, a1.w};
            float bc[8] = {b0.x, b0.y, b0.z, b0.w, b1.x, b1.y, b1.z, b1.w};
#pragma unroll
            for (int i = 0; i < 8; ++i)
#pragma unroll
                for (int j = 0; j < 8; ++j)
                    acc[i][j] = fmaf(ar[i], bc[j], acc[i][j]);
        }
        __syncthreads();
    }

    float4 bv0 = *(const float4*)&bias[n0 + tn * 4];
    float4 bv1 = *(const float4*)&bias[n0 + 64 + tn * 4];
    const float bb[8] = {bv0.x, bv0.y, bv0.z, bv0.w, bv1.x, bv1.y, bv1.z, bv1.w};
#pragma unroll
    for (int i = 0; i < 8; ++i) {
        const size_t rowoff = (size_t)(m0 + tm * 8 + i) * 512 + n0;
        float4 o0, o1;
        o0.x = acc[i][0] + bb[0]; o0.y = acc[i][1] + bb[1];
        o0.z = acc[i][2] + bb[2]; o0.w = acc[i][3] + bb[3];
        o1.x = acc[i][4] + bb[4]; o1.y = acc[i][5] + bb[5];
        o1.z = acc[i][6] + bb[6]; o1.w = acc[i][7] + bb[7];
        *(float4*)&C[rowoff + tn * 4] = o0;
        *(float4*)&C[rowoff + 64 + tn * 4] = o1;
    }
}

// fast tanh: 1 - 2/(exp2(2*log2e*x)+1); exact at +/-inf, ~1e-6 abs error
__device__ __forceinline__ float fast_tanh(float x)
{
    const float e = __builtin_amdgcn_exp2f(x * 2.88539008177793f);
    return fmaf(-2.0f, __builtin_amdgcn_rcpf(e + 1.0f), 1.0f);
}

// ---------------------------------------------------------------------------
// Recurrent scan. Persistent cooperative kernel, 256 WGs x 512 threads,
// 1 WG/CU (forced by 136 KB LDS). Group g (32 groups) = batch pair (2g,2g+1),
// 8 slice-WGs (bid = g + 32s -> same XCD under round-robin dispatch);
// slice s owns rows [64s, 64s+64), W-slice f32 in LDS (128 KB).
//
// W LDS layout (conflict-free): per-wave block Wv4[w*1024 + j*64 + l] holding
// W[base + w*8 + (l&7)][float4 col (l>>3)*16 + j] -> at each j a wave reads
// 64 CONSECUTIVE float4s (1 KB contiguous).
// h LDS: 17-float4 row pad -> the 8 kc broadcast groups hit distinct banks.
//
// Sync (two-tier, placement-safe):
//  - fast copy: workgroup-scope atomic store (plain global_store_dwordx2,
//    write-through L1 -> the XCD's shared L2); pollers read with plain
//    wg-scope loads refreshed by buffer_inv (L1-only invalidate) -> L2-hit RT.
//  - safe copy: agent-scope relaxed store to MALL; pollers escalate to it
//    after 64 failed spins -> correct even if WGs land on different XCDs.
// Tagged u64 {step+1, h bits}; parity double-buffer (race proof rounds 2-5).
// ---------------------------------------------------------------------------
__global__ __launch_bounds__(512, 2)
void rnn_scan(const float* __restrict__ proj, const float* __restrict__ Whh,
              const float* __restrict__ bhh, float* __restrict__ out,
              float* __restrict__ hidden,
              unsigned long long* __restrict__ hfast,
              unsigned long long* __restrict__ hsafe)
{
    extern __shared__ float lds[];
    float4* Wv4 = (float4*)lds;              // 8192 float4 = 128 KB
    float4* hS4 = (float4*)(lds + 32768);    // [p][b][136] float4 (17-pad)
    float*  hSf = lds + 32768;               // scalar view, 2176 floats

    const int t    = threadIdx.x;
    const int bid  = blockIdx.x;
    const int g    = bid & 31;               // group = batch pair
    const int s    = bid >> 5;               // slice 0..7 (stride 32 -> same XCD)
    const int b0   = g * 2;
    const int base = s * 64;
    const int w    = t >> 6;                 // wave 0..7
    const int l    = t & 63;
    const int rr   = l & 7;                  // row-in-wave
    const int kc   = l >> 3;                 // k-chunk 0..7 (64 k each)
    const int row  = base + w * 8 + rr;      // output row (64 per WG)

    // ---- one-time: W slice -> LDS in per-wave-block layout ----
    const float4* Wg4 = (const float4*)Whh;
    {
        const int k0 = kc * 16;
#pragma unroll
        for (int j = 0; j < 16; ++j)
            Wv4[w * 1024 + j * 64 + l] = Wg4[(size_t)row * 128 + k0 + j];
    }
    const bool pub  = (kc < 2);
    const float breg = pub ? bhh[row] : 0.f;

    // init both h parities to 0 (= h_init; also covers step-0 self-route)
    for (int i = t; i < 2176; i += 512) hSf[i] = 0.f;
    __syncthreads();

    const bool own  = (t >= base) && (t < base + 64);   // slot hid in own rows
    const int  pado = (t >> 6) * 68 + (t & 63);          // padded scalar offset

    // proj pipeline: value for step 0 (publisher kc selects batch b0+kc)
    float pv_next = 0.f;
    if (pub) pv_next = proj[(size_t)(b0 + kc) * HID + row];

    const unsigned long long* gf = hfast + (size_t)g * 2048;
    const unsigned long long* gs = hsafe + (size_t)g * 2048;
    unsigned long long* pf = hfast + (size_t)g * 2048;
    unsigned long long* ps = hsafe + (size_t)g * 2048;

    for (int step = 0; step < SEQ; ++step) {
        const int p = step & 1;

        const float pv = pv_next;
        if (pub && step + 1 < SEQ)
            pv_next = proj[((size_t)(step + 1) * BATCH + (b0 + kc)) * HID + row];

        // ---- poll 2 slots (b=0: hid t; b=1: hid t), stage into hS[p] ----
        if (!own) {
            const unsigned int want = (unsigned int)step;
            const unsigned long long* f0 = gf + (size_t)p * 1024 + t;
            const unsigned long long* f1 = f0 + 512;
            unsigned long long x0 = 0, x1 = 0;
            bool ok0 = false, ok1 = false;
            int spins = 0;
            for (;;) {
                asm volatile("buffer_inv" ::: "memory");   // L1-only refresh
                if (!ok0) {
                    x0 = __hip_atomic_load(f0, __ATOMIC_RELAXED, __HIP_MEMORY_SCOPE_WORKGROUP);
                    ok0 = (unsigned int)(x0 >> 32) == want;
                }
                if (!ok1) {
                    x1 = __hip_atomic_load(f1, __ATOMIC_RELAXED, __HIP_MEMORY_SCOPE_WORKGROUP);
                    ok1 = (unsigned int)(x1 >> 32) == want;
                }
                if (ok0 & ok1) break;
                if (++spins > 64) {                        // cross-XCD fallback
                    if (!ok0) {
                        x0 = __hip_atomic_load(gs + (size_t)p * 1024 + t,
                                               __ATOMIC_RELAXED, __HIP_MEMORY_SCOPE_AGENT);
                        ok0 = (unsigned int)(x0 >> 32) == want;
                    }
                    if (!ok1) {
                        x1 = __hip_atomic_load(gs + (size_t)p * 1024 + 512 + t,
                                               __ATOMIC_RELAXED, __HIP_MEMORY_SCOPE_AGENT);
                        ok1 = (unsigned int)(x1 >> 32) == want;
                    }
                    if (ok0 & ok1) break;
                }
                __builtin_amdgcn_s_sleep(1);
            }
            hSf[p * 1088 + pado]       = __uint_as_float((unsigned int)x0);
            hSf[p * 1088 + 544 + pado] = __uint_as_float((unsigned int)x1);
        }
        __syncthreads();   // the ONLY barrier per step

        // ---- matvec: wave-block W (contiguous) x broadcast h (padded) ----
        const float4* wb = Wv4 + w * 1024 + l;
        const float4* h0 = hS4 + p * 272 + kc * 17;
        const float4* h1 = h0 + 136;
        float a0e = 0.f, a0o = 0.f, a1e = 0.f, a1o = 0.f;
#pragma unroll
        for (int j = 0; j < 16; j += 2) {
            float4 wa = wb[j * 64];
            float4 wc = wb[(j + 1) * 64];
            float4 p0 = h0[j], p1 = h0[j + 1];
            float4 q0 = h1[j], q1 = h1[j + 1];
            a0e = fmaf(wa.x, p0.x, a0e); a0e = fmaf(wa.y, p0.y, a0e);
            a0e = fmaf(wa.z, p0.z, a0e); a0e = fmaf(wa.w, p0.w, a0e);
            a1e = fmaf(wa.x, q0.x, a1e); a1e = fmaf(wa.y, q0.y, a1e);
            a1e = fmaf(wa.z, q0.z, a1e); a1e = fmaf(wa.w, q0.w, a1e);
            a0o = fmaf(wc.x, p1.x, a0o); a0o = fmaf(wc.y, p1.y, a0o);
            a0o = fmaf(wc.z, p1.z, a0o); a0o = fmaf(wc.w, p1.w, a0o);
            a1o = fmaf(wc.x, q1.x, a1o); a1o = fmaf(wc.y, q1.y, a1o);
            a1o = fmaf(wc.z, q1.z, a1o); a1o = fmaf(wc.w, q1.w, a1o);
        }
        float s0 = a0e + a0o;
        float s1 = a1e + a1o;
        // butterfly over the kc bits (l^8, l^16, l^32): all lanes get totals
        s0 += __shfl_xor(s0, 8, 64);  s1 += __shfl_xor(s1, 8, 64);
        s0 += __shfl_xor(s0, 16, 64); s1 += __shfl_xor(s1, 16, 64);
        s0 += __shfl_xor(s0, 32, 64); s1 += __shfl_xor(s1, 32, 64);

        // ---- tanh + publish (kc==0 -> batch b0, kc==1 -> b0+1) ----
        if (pub) {
            const float sum = (kc == 0) ? s0 : s1;
            const int   bb  = b0 + kc;
            const float hn  = fast_tanh(pv + breg + sum);
            out[((size_t)step * BATCH + bb) * HID + row] = hn;
            const unsigned long long pk =
                ((unsigned long long)(unsigned int)(step + 1) << 32) |
                (unsigned long long)__float_as_uint(hn);
            const size_t oi = (size_t)(p ^ 1) * 1024 + (size_t)kc * 512 + row;
            __hip_atomic_store(pf + oi, pk, __ATOMIC_RELAXED, __HIP_MEMORY_SCOPE_WORKGROUP);
            __hip_atomic_store(ps + oi, pk, __ATOMIC_RELAXED, __HIP_MEMORY_SCOPE_AGENT);
            hSf[(p ^ 1) * 1088 + kc * 544 + (row >> 6) * 68 + (row & 63)] = hn;
            if (step == SEQ - 1) hidden[(size_t)bb * HID + row] = hn;
        }
        // no trailing barrier: next step's pre-barrier LDS writes touch only
        // parity p^1 (disjoint from this step's hS[p] reads); overwrites of
        // hS[p] can only happen after the NEXT barrier, which gates on all
        // threads finishing this step's reads.
    }
}

// ---------------------------------------------------------------------------
extern "C" void kernel_launch(void* const* d_in, const int* in_sizes, int n_in,
                              void* d_out, int out_size, void* d_ws, size_t ws_size,
                              hipStream_t stream)
{
    (void)in_sizes; (void)n_in; (void)out_size; (void)ws_size;

    const float* x    = (const float*)d_in[0];
    const float* Wih0 = (const float*)d_in[1];
    const float* Whh0 = (const float*)d_in[2];
    const float* bih0 = (const float*)d_in[3];
    const float* bhh0 = (const float*)d_in[4];
    const float* Wih1 = (const float*)d_in[5];
    const float* Whh1 = (const float*)d_in[6];
    const float* bih1 = (const float*)d_in[7];
    const float* bhh1 = (const float*)d_in[8];

    float* out1   = (float*)d_out;                        // [S][B][H]
    float* hidden = out1 + (size_t)SEQ * BATCH * HID;     // [2][B][H]

    float* proj = (float*)d_ws;                           // [S][B][H] f32
    // per-layer tagged h buffers: fast (XCD-L2 path) + safe (MALL path),
    // each [32 groups][2 parity][2 batch][512] u64
    unsigned long long* hfastA = (unsigned long long*)(proj + (size_t)SEQ * BATCH * HID);
    unsigned long long* hsafeA = hfastA + (size_t)32 * 2048;
    unsigned long long* hfastB = hsafeA + (size_t)32 * 2048;
    unsigned long long* hsafeB = hfastB + (size_t)32 * 2048;

    // zero all four tag arrays (tag 0 == epoch 0, h = 0)
    hipMemsetAsync(hfastA, 0, (size_t)4 * 32 * 2048 * sizeof(unsigned long long),
                   stream);

    const size_t shmem = (size_t)(32768 + 2176) * sizeof(float);  // 139776 B
    (void)hipFuncSetAttribute((const void*)rnn_scan,
                              hipFuncAttributeMaxDynamicSharedMemorySize, (int)shmem);

    // ---- layer 0 ----
    proj_gemm<<<dim3(4096), dim3(256), 0, stream>>>(x, Wih0, bih0, proj);
    {
        const float* p = proj; const float* w = Whh0; const float* bb = bhh0;
        float* o = out1; float* hd = hidden;
        unsigned long long* hf = hfastA; unsigned long long* hs = hsafeA;
        void* args[] = {&p, &w, &bb, &o, &hd, &hf, &hs};
        hipLaunchCooperativeKernel((const void*)rnn_scan, dim3(256), dim3(512),
                                   args, (unsigned)shmem, stream);
    }

    // ---- layer 1 (out0 staged in d_out's out1 region) ----
    proj_gemm<<<dim3(4096), dim3(256), 0, stream>>>(out1, Wih1, bih1, proj);
    {
        const float* p = proj; const float* w = Whh1; const float* bb = bhh1;
        float* o = out1; float* hd = hidden + BATCH * HID;
        unsigned long long* hf = hfastB; unsigned long long* hs = hsafeB;
        void* args[] = {&p, &w, &bb, &o, &hd, &hf, &hs};
        hipLaunchCooperativeKernel((const void*)rnn_scan, dim3(256), dim3(512),
                                   args, (unsigned)shmem, stream);
    }
}

// Round 9
// 9655.082 us; speedup vs baseline: 8.3221x; 8.3221x over previous
//
#include <hip/hip_runtime.h>
#include <cstdint>
#include <cstddef>

#define SEQ   2048
#define BATCH 64
#define HID   512

// ---------------------------------------------------------------------------
// proj GEMM: C[m][n] = sum_k A[m][k] * W[n][k] + bias[n]
// ---------------------------------------------------------------------------
__global__ __launch_bounds__(256)
void proj_gemm(const float* __restrict__ A, const float* __restrict__ W,
               const float* __restrict__ bias, float* __restrict__ C)
{
    __shared__ float As[16][132];
    __shared__ float Bs[16][132];
    const int t  = threadIdx.x;
    const int bm = blockIdx.x >> 2;
    const int bn = blockIdx.x & 3;
    const int m0 = bm * 128;
    const int n0 = bn * 128;
    const int tn = t & 15;
    const int tm = t >> 4;

    float acc[8][8];
#pragma unroll
    for (int i = 0; i < 8; ++i)
#pragma unroll
        for (int j = 0; j < 8; ++j) acc[i][j] = 0.f;

    const int lrow = t >> 2;
    const int lk4  = t & 3;

    for (int kk = 0; kk < 512; kk += 16) {
#pragma unroll
        for (int i = 0; i < 2; ++i) {
            const int row = lrow + i * 64;
            float4 va = *(const float4*)&A[(size_t)(m0 + row) * 512 + kk + lk4 * 4];
            As[lk4 * 4 + 0][row] = va.x;
            As[lk4 * 4 + 1][row] = va.y;
            As[lk4 * 4 + 2][row] = va.z;
            As[lk4 * 4 + 3][row] = va.w;
            float4 vb = *(const float4*)&W[(size_t)(n0 + row) * 512 + kk + lk4 * 4];
            Bs[lk4 * 4 + 0][row] = vb.x;
            Bs[lk4 * 4 + 1][row] = vb.y;
            Bs[lk4 * 4 + 2][row] = vb.z;
            Bs[lk4 * 4 + 3][row] = vb.w;
        }
        __syncthreads();
#pragma unroll
        for (int k = 0; k < 16; ++k) {
            float4 a0 = *(const float4*)&As[k][tm * 8];
            float4 a1 = *(const float4*)&As[k][tm * 8 + 4];
            float4 b0 = *(const float4*)&Bs[k][tn * 4];
            float4 b1 = *(const float4*)&Bs[k][64 + tn * 4];
            float ar[8] = {a0.x, a0.y, a0.z, a0.w, a1.x, a1.y, a1.z, a1.w};
            float bc[8] = {b0.x, b0.y, b0.z, b0.w, b1.x, b1.y, b1.z, b1.w};
#pragma unroll
            for (int i = 0; i < 8; ++i)
#pragma unroll
                for (int j = 0; j < 8; ++j)
                    acc[i][j] = fmaf(ar[i], bc[j], acc[i][j]);
        }
        __syncthreads();
    }

    float4 bv0 = *(const float4*)&bias[n0 + tn * 4];
    float4 bv1 = *(const float4*)&bias[n0 + 64 + tn * 4];
    const float bb[8] = {bv0.x, bv0.y, bv0.z, bv0.w, bv1.x, bv1.y, bv1.z, bv1.w};
#pragma unroll
    for (int i = 0; i < 8; ++i) {
        const size_t rowoff = (size_t)(m0 + tm * 8 + i) * 512 + n0;
        float4 o0, o1;
        o0.x = acc[i][0] + bb[0]; o0.y = acc[i][1] + bb[1];
        o0.z = acc[i][2] + bb[2]; o0.w = acc[i][3] + bb[3];
        o1.x = acc[i][4] + bb[4]; o1.y = acc[i][5] + bb[5];
        o1.z = acc[i][6] + bb[6]; o1.w = acc[i][7] + bb[7];
        *(float4*)&C[rowoff + tn * 4] = o0;
        *(float4*)&C[rowoff + 64 + tn * 4] = o1;
    }
}

// fast tanh: 1 - 2/(exp2(2*log2e*x)+1); exact at +/-inf, ~1e-6 abs error
__device__ __forceinline__ float fast_tanh(float x)
{
    const float e = __builtin_amdgcn_exp2f(x * 2.88539008177793f);
    return fmaf(-2.0f, __builtin_amdgcn_rcpf(e + 1.0f), 1.0f);
}

// ---------------------------------------------------------------------------
// Recurrent scan. Persistent cooperative kernel, 256 WGs x 512 threads,
// 1 WG/CU (forced by 136 KB LDS -> all 256 CUs active).
// Group g (32 groups) = batch pair (2g, 2g+1); 8 slice-WGs per group
// (bid = g + 32s -> all group members on the same XCD, speed-only).
// Slice s owns rows [64s, 64s+64); its W-slice lives in LDS (128 KB):
//   Wv4[w*1024 + j*64 + l] = W[base + w*8 + (l&7)][float4 (l>>3)*16 + j]
//   -> per j a wave reads 64 CONSECUTIVE float4s (conflict-free).
// h LDS: 17-float4 row pad -> 8 kc broadcast groups tile all 32 banks.
//
// Sync = round-4 proven scheme (NO cache ops anywhere): tagged u64
// {step+1, f32 h bits} via RELAXED AGENT-scope atomics (bypass L1/L2 to
// coherence point), s_sleep(1) poll, parity double-buffer (read slot
// step&1, write slot (step+1)&1) closing the overwrite race; own 64 rows
// self-routed through LDS by publishers. ONE barrier per step.
// ---------------------------------------------------------------------------
__global__ __launch_bounds__(512, 2)
void rnn_scan(const float* __restrict__ proj, const float* __restrict__ Whh,
              const float* __restrict__ bhh, float* __restrict__ out,
              float* __restrict__ hidden, unsigned long long* __restrict__ hbuf)
{
    extern __shared__ float lds[];
    float4* Wv4 = (float4*)lds;              // 8192 float4 = 128 KB
    float4* hS4 = (float4*)(lds + 32768);    // [p][b][136] float4 (17-pad)
    float*  hSf = lds + 32768;               // scalar view, 2176 floats

    const int t    = threadIdx.x;
    const int bid  = blockIdx.x;
    const int g    = bid & 31;               // group = batch pair
    const int s    = bid >> 5;               // slice 0..7 (same XCD)
    const int b0   = g * 2;
    const int base = s * 64;
    const int w    = t >> 6;                 // wave 0..7
    const int l    = t & 63;
    const int rr   = l & 7;                  // row-in-wave
    const int kc   = l >> 3;                 // k-chunk 0..7 (64 k each)
    const int row  = base + w * 8 + rr;      // output row (64 per WG)

    // ---- one-time: W slice -> LDS in per-wave-block layout ----
    const float4* Wg4 = (const float4*)Whh;
    {
        const int k0 = kc * 16;
#pragma unroll
        for (int j = 0; j < 16; ++j)
            Wv4[w * 1024 + j * 64 + l] = Wg4[(size_t)row * 128 + k0 + j];
    }
    const bool pub  = (kc < 2);
    const float breg = pub ? bhh[row] : 0.f;

    // init both h parities to 0 (= h_init; also covers step-0 self-route)
    for (int i = t; i < 2176; i += 512) hSf[i] = 0.f;
    __syncthreads();

    const bool own  = (t >= base) && (t < base + 64);   // hid t self-routed
    const int  pado = (t >> 6) * 68 + (t & 63);         // padded scalar offset

    // proj pipeline: value for step 0 (publisher kc selects batch b0+kc)
    float pv_next = 0.f;
    if (pub) pv_next = proj[(size_t)(b0 + kc) * HID + row];

    unsigned long long* gb = hbuf + (size_t)g * 4096;   // [p][b][512] u64

    for (int step = 0; step < SEQ; ++step) {
        const int p = step & 1;

        const float pv = pv_next;
        if (pub && step + 1 < SEQ)
            pv_next = proj[((size_t)(step + 1) * BATCH + (b0 + kc)) * HID + row];

        // ---- poll 2 tagged u64 (hid t, batch 0/1), stage into hS[p] ----
        if (!own) {
            const unsigned int want = (unsigned int)step;
            const unsigned long long* f0 = gb + (size_t)p * 2048 + t;
            const unsigned long long* f1 = f0 + 512;
            unsigned long long x0 = 0, x1 = 0;
            bool ok0 = false, ok1 = false;
            int spins = 0;
            for (;;) {
                if (!ok0) {
                    x0 = __hip_atomic_load(f0, __ATOMIC_RELAXED, __HIP_MEMORY_SCOPE_AGENT);
                    ok0 = (unsigned int)(x0 >> 32) == want;
                }
                if (!ok1) {
                    x1 = __hip_atomic_load(f1, __ATOMIC_RELAXED, __HIP_MEMORY_SCOPE_AGENT);
                    ok1 = (unsigned int)(x1 >> 32) == want;
                }
                if (ok0 & ok1) break;
                __builtin_amdgcn_s_sleep(1);
                if (++spins > 4096) {              // hang-proofing only
                    __builtin_amdgcn_fence(__ATOMIC_ACQUIRE, "agent");
                    spins = 0;
                }
            }
            hSf[p * 1088 + pado]       = __uint_as_float((unsigned int)x0);
            hSf[p * 1088 + 544 + pado] = __uint_as_float((unsigned int)x1);
        }
        __syncthreads();   // the ONLY barrier per step

        // ---- matvec: wave-block W (contiguous) x broadcast h (padded) ----
        const float4* wb = Wv4 + w * 1024 + l;
        const float4* h0 = hS4 + p * 272 + kc * 17;
        const float4* h1 = h0 + 136;
        float a0e = 0.f, a0o = 0.f, a1e = 0.f, a1o = 0.f;
#pragma unroll
        for (int j = 0; j < 16; j += 2) {
            float4 wa = wb[j * 64];
            float4 wc = wb[(j + 1) * 64];
            float4 p0 = h0[j], p1 = h0[j + 1];
            float4 q0 = h1[j], q1 = h1[j + 1];
            a0e = fmaf(wa.x, p0.x, a0e); a0e = fmaf(wa.y, p0.y, a0e);
            a0e = fmaf(wa.z, p0.z, a0e); a0e = fmaf(wa.w, p0.w, a0e);
            a1e = fmaf(wa.x, q0.x, a1e); a1e = fmaf(wa.y, q0.y, a1e);
            a1e = fmaf(wa.z, q0.z, a1e); a1e = fmaf(wa.w, q0.w, a1e);
            a0o = fmaf(wc.x, p1.x, a0o); a0o = fmaf(wc.y, p1.y, a0o);
            a0o = fmaf(wc.z, p1.z, a0o); a0o = fmaf(wc.w, p1.w, a0o);
            a1o = fmaf(wc.x, q1.x, a1o); a1o = fmaf(wc.y, q1.y, a1o);
            a1o = fmaf(wc.z, q1.z, a1o); a1o = fmaf(wc.w, q1.w, a1o);
        }
        float s0 = a0e + a0o;
        float s1 = a1e + a1o;
        // butterfly over the kc bits (l^8, l^16, l^32): all lanes get totals
        s0 += __shfl_xor(s0, 8, 64);  s1 += __shfl_xor(s1, 8, 64);
        s0 += __shfl_xor(s0, 16, 64); s1 += __shfl_xor(s1, 16, 64);
        s0 += __shfl_xor(s0, 32, 64); s1 += __shfl_xor(s1, 32, 64);

        // ---- tanh + publish (kc==0 -> batch b0, kc==1 -> b0+1) ----
        if (pub) {
            const float sum = (kc == 0) ? s0 : s1;
            const int   bb  = b0 + kc;
            const float hn  = fast_tanh(pv + breg + sum);
            out[((size_t)step * BATCH + bb) * HID + row] = hn;
            const unsigned long long pk =
                ((unsigned long long)(unsigned int)(step + 1) << 32) |
                (unsigned long long)__float_as_uint(hn);
            __hip_atomic_store(gb + (size_t)(p ^ 1) * 2048 + (size_t)kc * 512 + row,
                               pk, __ATOMIC_RELAXED, __HIP_MEMORY_SCOPE_AGENT);
            hSf[(p ^ 1) * 1088 + kc * 544 + (row >> 6) * 68 + (row & 63)] = hn;
            if (step == SEQ - 1) hidden[(size_t)bb * HID + row] = hn;
        }
        // no trailing barrier: next step's pre-barrier LDS writes touch only
        // parity p^1 (disjoint from this step's hS[p] reads); hS[p] can only
        // be overwritten after the NEXT barrier, which gates on all threads
        // finishing this step's reads.
    }
}

// ---------------------------------------------------------------------------
extern "C" void kernel_launch(void* const* d_in, const int* in_sizes, int n_in,
                              void* d_out, int out_size, void* d_ws, size_t ws_size,
                              hipStream_t stream)
{
    (void)in_sizes; (void)n_in; (void)out_size; (void)ws_size;

    const float* x    = (const float*)d_in[0];
    const float* Wih0 = (const float*)d_in[1];
    const float* Whh0 = (const float*)d_in[2];
    const float* bih0 = (const float*)d_in[3];
    const float* bhh0 = (const float*)d_in[4];
    const float* Wih1 = (const float*)d_in[5];
    const float* Whh1 = (const float*)d_in[6];
    const float* bih1 = (const float*)d_in[7];
    const float* bhh1 = (const float*)d_in[8];

    float* out1   = (float*)d_out;                        // [S][B][H]
    float* hidden = out1 + (size_t)SEQ * BATCH * HID;     // [2][B][H]

    float* proj = (float*)d_ws;                           // [S][B][H] f32
    // per-layer tagged h buffers: [32 groups][2 parity][2 batch][512] u64
    unsigned long long* hbufA = (unsigned long long*)(proj + (size_t)SEQ * BATCH * HID);
    unsigned long long* hbufB = hbufA + (size_t)32 * 4096;

    // zero both layers' tag arrays (tag 0 == epoch 0, h = 0)
    hipMemsetAsync(hbufA, 0, (size_t)2 * 32 * 4096 * sizeof(unsigned long long),
                   stream);

    const size_t shmem = (size_t)(32768 + 2176) * sizeof(float);  // 139776 B
    (void)hipFuncSetAttribute((const void*)rnn_scan,
                              hipFuncAttributeMaxDynamicSharedMemorySize, (int)shmem);

    // ---- layer 0 ----
    proj_gemm<<<dim3(4096), dim3(256), 0, stream>>>(x, Wih0, bih0, proj);
    {
        const float* p = proj; const float* w = Whh0; const float* bb = bhh0;
        float* o = out1; float* hd = hidden; unsigned long long* hb = hbufA;
        void* args[] = {&p, &w, &bb, &o, &hd, &hb};
        hipLaunchCooperativeKernel((const void*)rnn_scan, dim3(256), dim3(512),
                                   args, (unsigned)shmem, stream);
    }

    // ---- layer 1 (out0 staged in d_out's out1 region) ----
    proj_gemm<<<dim3(4096), dim3(256), 0, stream>>>(out1, Wih1, bih1, proj);
    {
        const float* p = proj; const float* w = Whh1; const float* bb = bhh1;
        float* o = out1; float* hd = hidden + BATCH * HID; unsigned long long* hb = hbufB;
        void* args[] = {&p, &w, &bb, &o, &hd, &hb};
        hipLaunchCooperativeKernel((const void*)rnn_scan, dim3(256), dim3(512),
                                   args, (unsigned)shmem, stream);
    }
}